// Round 6
// baseline (81.300 us; speedup 1.0000x reference)
//
#include <hip/hip_runtime.h>
#include <math.h>

#define BINS 10
#define NCLS 1000
#define EPSV 1e-8f

// Full-wave (64-lane) sum via DPP: 6 dependent VALU adds (~50 cy) instead of
// 6 ds_bpermute (~720 cy). Valid total lands in lane 63.
__device__ __forceinline__ float dpp_reduce_add_lane63(float x) {
    int t;
    t = __builtin_amdgcn_update_dpp(0, __float_as_int(x), 0x111, 0xF, 0xF, true); x += __int_as_float(t); // row_shr:1
    t = __builtin_amdgcn_update_dpp(0, __float_as_int(x), 0x112, 0xF, 0xF, true); x += __int_as_float(t); // row_shr:2
    t = __builtin_amdgcn_update_dpp(0, __float_as_int(x), 0x114, 0xF, 0xF, true); x += __int_as_float(t); // row_shr:4
    t = __builtin_amdgcn_update_dpp(0, __float_as_int(x), 0x118, 0xF, 0xF, true); x += __int_as_float(t); // row_shr:8
    t = __builtin_amdgcn_update_dpp(0, __float_as_int(x), 0x142, 0xF, 0xF, true); x += __int_as_float(t); // row_bcast:15
    t = __builtin_amdgcn_update_dpp(0, __float_as_int(x), 0x143, 0xF, 0xF, true); x += __int_as_float(t); // row_bcast:31
    return x; // lane 63 holds the full 64-lane sum
}

// Tree-shaped sum of exp over 16 values (depth 4).
__device__ __forceinline__ float exp16_sum(const float4& v0, const float4& v1,
                                           const float4& v2, const float4& v3) {
    float a0 = __expf(v0.x) + __expf(v0.y), a1 = __expf(v0.z) + __expf(v0.w);
    float a2 = __expf(v1.x) + __expf(v1.y), a3 = __expf(v1.z) + __expf(v1.w);
    float a4 = __expf(v2.x) + __expf(v2.y), a5 = __expf(v2.z) + __expf(v2.w);
    float a6 = __expf(v3.x) + __expf(v3.y), a7 = __expf(v3.z) + __expf(v3.w);
    float b0 = a0 + a1, b1 = a2 + a3, b2 = a4 + a5, b3 = a6 + a7;
    return (b0 + b1) + (b2 + b3);
}

// Fused single kernel: R5's pass1 main loop (1 row/stage, 4 register phases,
// 3 batches in flight per wave) + per-block partial stores + last-block-done
// final reduction (release fence -> counter atomic -> acquire fence; the
// device-scope fences handle cross-XCD L2 non-coherence, partials served
// from L3). Counter must be zeroed by a 64B memset each call (harness
// poisons ws). __launch_bounds__(256,4) pins VGPR<=128 so 4 blocks/CU
// (16 waves/CU) stay resident.
__global__ __launch_bounds__(256, 4) void ghmc_fused(
    const float* __restrict__ pred,
    const int*   __restrict__ target,
    int*   __restrict__ counter,
    int*   __restrict__ pcnt,
    float* __restrict__ psum,
    float* __restrict__ out,
    int nrows, int nblk)
{
    __shared__ int   s_cnt[BINS];
    __shared__ float s_sum[BINS];
    if (threadIdx.x < BINS) { s_cnt[threadIdx.x] = 0; s_sum[threadIdx.x] = 0.0f; }
    __syncthreads();

    const int lane = threadIdx.x & 63;
    const int wv   = threadIdx.x >> 6;
    const int base = blockIdx.x * 64 + wv * 16;   // wave owns rows base..base+15
    const float NEG = -INFINITY;

    // Preload all 16 targets (wave-uniform addresses -> scalar loads).
    int tgt[16];
    #pragma unroll
    for (int k = 0; k < 16; ++k) tgt[k] = target[min(base + k, nrows - 1)];

    float4 C0[4], C1[4], C2[4], C3[4];
    float  pt[4];

#define LOADK(kk, pp) do {                                                    \
    const int r_ = min(base + (kk), nrows - 1);                               \
    const float4* rp_ = (const float4*)(pred + (size_t)r_ * NCLS);            \
    C0[pp] = rp_[lane]; C1[pp] = rp_[lane + 64]; C2[pp] = rp_[lane + 128];    \
    if (lane < 58) C3[pp] = rp_[lane + 192];                                  \
    else           C3[pp] = make_float4(NEG, NEG, NEG, NEG);                  \
    pt[pp] = pred[(size_t)r_ * NCLS + tgt[kk]];                               \
} while (0)

    LOADK(0, 0);  LOADK(1, 1);  LOADK(2, 2);   // prologue: 3 batches in flight

    #pragma unroll
    for (int k = 0; k < 16; ++k) {
        const int p = k & 3;
        if (k < 13) LOADK(k + 3, (k + 3) & 3);   // keep 3 batches outstanding

        float s = exp16_sum(C0[p], C1[p], C2[p], C3[p]);
        s = dpp_reduce_add_lane63(s);

        if (lane == 63 && base + k < nrows) {
            const float loss = -pt[p] + __logf(s + EPSV);
            const float g = 1.0f - __expf(pt[p]) / s;
            int b = (int)floorf(g * 10.0f);
            b = min(max(b, 0), BINS - 1);
            atomicAdd(&s_cnt[b], 1);
            atomicAdd(&s_sum[b], loss);
        }
    }
#undef LOADK

    __syncthreads();
    if (threadIdx.x < BINS) {
        pcnt[blockIdx.x * BINS + threadIdx.x] = s_cnt[threadIdx.x];
        psum[blockIdx.x * BINS + threadIdx.x] = s_sum[threadIdx.x];
        __threadfence();   // release: partials visible device-wide (to L3)
    }
    __syncthreads();

    __shared__ int s_last;
    if (threadIdx.x == 0)
        s_last = (atomicAdd(counter, 1) == nblk - 1);
    __syncthreads();
    if (!s_last) return;

    // ---- last block: reduce nblk x 10 partials and emit the scalar ----
    __threadfence();       // acquire: see all blocks' partials

    float cnt[BINS], sum[BINS];
    #pragma unroll
    for (int b = 0; b < BINS; ++b) { cnt[b] = 0.0f; sum[b] = 0.0f; }

    for (int blk = threadIdx.x; blk < nblk; blk += 256) {
        #pragma unroll
        for (int b = 0; b < BINS; ++b) {
            cnt[b] += (float)pcnt[blk * BINS + b];   // counts <= 65536: exact in f32
            sum[b] += psum[blk * BINS + b];
        }
    }

    __shared__ float sc[4][BINS], ss[4][BINS];
    #pragma unroll
    for (int b = 0; b < BINS; ++b) {
        const float c = dpp_reduce_add_lane63(cnt[b]);
        const float s = dpp_reduce_add_lane63(sum[b]);
        if (lane == 63) { sc[wv][b] = c; ss[wv][b] = s; }
    }
    __syncthreads();

    if (threadIdx.x == 0) {
        int n = 0;
        float acc = 0.0f;
        for (int b = 0; b < BINS; ++b) {
            const float c = sc[0][b] + sc[1][b] + sc[2][b] + sc[3][b];
            const float s = ss[0][b] + ss[1][b] + ss[2][b] + ss[3][b];
            if (c > 0.0f) { n += 1; acc += s / c; }
        }
        out[0] = acc / (float)max(n, 1);
    }
}

// ---------------- fallback path (tiny ws): R5's two-kernel scheme ----------
__global__ __launch_bounds__(256) void ghmc_pass1_atomic(
    const float* __restrict__ pred,
    const int*   __restrict__ target,
    int*   __restrict__ gcnt,
    float* __restrict__ gsum,
    int nrows)
{
    __shared__ int   s_cnt[BINS];
    __shared__ float s_sum[BINS];
    if (threadIdx.x < BINS) { s_cnt[threadIdx.x] = 0; s_sum[threadIdx.x] = 0.0f; }
    __syncthreads();

    const int lane = threadIdx.x & 63;
    const int wv   = threadIdx.x >> 6;
    const int base = blockIdx.x * 64 + wv * 16;
    const float NEG = -INFINITY;

    int tgt[16];
    #pragma unroll
    for (int k = 0; k < 16; ++k) tgt[k] = target[min(base + k, nrows - 1)];

    float4 C0[4], C1[4], C2[4], C3[4];
    float  pt[4];

#define LOADK(kk, pp) do {                                                    \
    const int r_ = min(base + (kk), nrows - 1);                               \
    const float4* rp_ = (const float4*)(pred + (size_t)r_ * NCLS);            \
    C0[pp] = rp_[lane]; C1[pp] = rp_[lane + 64]; C2[pp] = rp_[lane + 128];    \
    if (lane < 58) C3[pp] = rp_[lane + 192];                                  \
    else           C3[pp] = make_float4(NEG, NEG, NEG, NEG);                  \
    pt[pp] = pred[(size_t)r_ * NCLS + tgt[kk]];                               \
} while (0)

    LOADK(0, 0);  LOADK(1, 1);  LOADK(2, 2);

    #pragma unroll
    for (int k = 0; k < 16; ++k) {
        const int p = k & 3;
        if (k < 13) LOADK(k + 3, (k + 3) & 3);

        float s = exp16_sum(C0[p], C1[p], C2[p], C3[p]);
        s = dpp_reduce_add_lane63(s);

        if (lane == 63 && base + k < nrows) {
            const float loss = -pt[p] + __logf(s + EPSV);
            const float g = 1.0f - __expf(pt[p]) / s;
            int b = (int)floorf(g * 10.0f);
            b = min(max(b, 0), BINS - 1);
            atomicAdd(&s_cnt[b], 1);
            atomicAdd(&s_sum[b], loss);
        }
    }
#undef LOADK

    __syncthreads();
    if (threadIdx.x < BINS && s_cnt[threadIdx.x] > 0) {
        atomicAdd(&gcnt[threadIdx.x], s_cnt[threadIdx.x]);
        atomicAdd(&gsum[threadIdx.x], s_sum[threadIdx.x]);
    }
}

__global__ void ghmc_pass2_small(const int* __restrict__ gcnt,
                                 const float* __restrict__ gsum,
                                 float* __restrict__ out)
{
    if (threadIdx.x == 0 && blockIdx.x == 0) {
        int n = 0;
        float acc = 0.0f;
        for (int b = 0; b < BINS; ++b) {
            if (gcnt[b] > 0) { n += 1; acc += gsum[b] / (float)gcnt[b]; }
        }
        out[0] = acc / (float)max(n, 1);
    }
}

extern "C" void kernel_launch(void* const* d_in, const int* in_sizes, int n_in,
                              void* d_out, int out_size, void* d_ws, size_t ws_size,
                              hipStream_t stream)
{
    const float* pred   = (const float*)d_in[0];
    const int*   target = (const int*)d_in[1];
    const int nrows  = in_sizes[1];            // 65536
    const int blocks = (nrows + 63) / 64;      // 1024

    const size_t part_bytes = (((size_t)blocks * BINS * sizeof(int)) + 63) & ~(size_t)63;
    const size_t need = 64 + 2 * part_bytes;   // counter | pcnt | psum

    if (ws_size >= need) {
        int*   counter = (int*)d_ws;
        int*   pcnt = (int*)((char*)d_ws + 64);
        float* psum = (float*)((char*)d_ws + 64 + part_bytes);
        hipMemsetAsync(d_ws, 0, 64, stream);   // zero the arrival counter
        ghmc_fused<<<blocks, 256, 0, stream>>>(pred, target, counter, pcnt, psum,
                                               (float*)d_out, nrows, blocks);
    } else {
        int*   gcnt = (int*)d_ws;
        float* gsum = (float*)((char*)d_ws + 64);
        hipMemsetAsync(d_ws, 0, 128, stream);
        ghmc_pass1_atomic<<<blocks, 256, 0, stream>>>(pred, target, gcnt, gsum, nrows);
        ghmc_pass2_small<<<1, 64, 0, stream>>>(gcnt, gsum, (float*)d_out);
    }
}

// Round 7
// 81.031 us; speedup vs baseline: 1.0033x; 1.0033x over previous
//
#include <hip/hip_runtime.h>
#include <math.h>

#define BINS 10
#define NCLS 1000
#define EPSV 1e-8f

// Full-wave (64-lane) sum via DPP: 6 dependent VALU adds (~50 cy) instead of
// 6 ds_bpermute (~720 cy). Valid total lands in lane 63.
__device__ __forceinline__ float dpp_reduce_add_lane63(float x) {
    int t;
    t = __builtin_amdgcn_update_dpp(0, __float_as_int(x), 0x111, 0xF, 0xF, true); x += __int_as_float(t); // row_shr:1
    t = __builtin_amdgcn_update_dpp(0, __float_as_int(x), 0x112, 0xF, 0xF, true); x += __int_as_float(t); // row_shr:2
    t = __builtin_amdgcn_update_dpp(0, __float_as_int(x), 0x114, 0xF, 0xF, true); x += __int_as_float(t); // row_shr:4
    t = __builtin_amdgcn_update_dpp(0, __float_as_int(x), 0x118, 0xF, 0xF, true); x += __int_as_float(t); // row_shr:8
    t = __builtin_amdgcn_update_dpp(0, __float_as_int(x), 0x142, 0xF, 0xF, true); x += __int_as_float(t); // row_bcast:15
    t = __builtin_amdgcn_update_dpp(0, __float_as_int(x), 0x143, 0xF, 0xF, true); x += __int_as_float(t); // row_bcast:31
    return x; // lane 63 holds the full 64-lane sum
}

// Tree-shaped sum of exp over 16 values (depth 4).
__device__ __forceinline__ float exp16_sum(const float4& v0, const float4& v1,
                                           const float4& v2, const float4& v3) {
    float a0 = __expf(v0.x) + __expf(v0.y), a1 = __expf(v0.z) + __expf(v0.w);
    float a2 = __expf(v1.x) + __expf(v1.y), a3 = __expf(v1.z) + __expf(v1.w);
    float a4 = __expf(v2.x) + __expf(v2.y), a5 = __expf(v2.z) + __expf(v2.w);
    float a6 = __expf(v3.x) + __expf(v3.y), a7 = __expf(v3.z) + __expf(v3.w);
    float b0 = a0 + a1, b1 = a2 + a3, b2 = a4 + a5, b3 = a6 + a7;
    return (b0 + b1) + (b2 + b3);
}

// Fused single kernel: R5's pass1 main loop (1 row/stage, 4 register phases,
// 3 batches in flight per wave) + per-block partial stores + last-block-done
// final reduction (release fence -> counter atomic -> acquire fence; the
// device-scope fences handle cross-XCD L2 non-coherence, partials served
// from L3). Counter must be zeroed by a 64B memset each call (harness
// poisons ws). __launch_bounds__(256,4) pins VGPR<=128 so 4 blocks/CU
// (16 waves/CU) stay resident.
__global__ __launch_bounds__(256, 4) void ghmc_fused(
    const float* __restrict__ pred,
    const int*   __restrict__ target,
    int*   __restrict__ counter,
    int*   __restrict__ pcnt,
    float* __restrict__ psum,
    float* __restrict__ out,
    int nrows, int nblk)
{
    __shared__ int   s_cnt[BINS];
    __shared__ float s_sum[BINS];
    if (threadIdx.x < BINS) { s_cnt[threadIdx.x] = 0; s_sum[threadIdx.x] = 0.0f; }
    __syncthreads();

    const int lane = threadIdx.x & 63;
    const int wv   = threadIdx.x >> 6;
    const int base = blockIdx.x * 64 + wv * 16;   // wave owns rows base..base+15
    const float NEG = -INFINITY;

    // Preload all 16 targets (wave-uniform addresses -> scalar loads).
    int tgt[16];
    #pragma unroll
    for (int k = 0; k < 16; ++k) tgt[k] = target[min(base + k, nrows - 1)];

    float4 C0[4], C1[4], C2[4], C3[4];
    float  pt[4];

#define LOADK(kk, pp) do {                                                    \
    const int r_ = min(base + (kk), nrows - 1);                               \
    const float4* rp_ = (const float4*)(pred + (size_t)r_ * NCLS);            \
    C0[pp] = rp_[lane]; C1[pp] = rp_[lane + 64]; C2[pp] = rp_[lane + 128];    \
    if (lane < 58) C3[pp] = rp_[lane + 192];                                  \
    else           C3[pp] = make_float4(NEG, NEG, NEG, NEG);                  \
    pt[pp] = pred[(size_t)r_ * NCLS + tgt[kk]];                               \
} while (0)

    LOADK(0, 0);  LOADK(1, 1);  LOADK(2, 2);   // prologue: 3 batches in flight

    #pragma unroll
    for (int k = 0; k < 16; ++k) {
        const int p = k & 3;
        if (k < 13) LOADK(k + 3, (k + 3) & 3);   // keep 3 batches outstanding

        float s = exp16_sum(C0[p], C1[p], C2[p], C3[p]);
        s = dpp_reduce_add_lane63(s);

        if (lane == 63 && base + k < nrows) {
            const float loss = -pt[p] + __logf(s + EPSV);
            const float g = 1.0f - __expf(pt[p]) / s;
            int b = (int)floorf(g * 10.0f);
            b = min(max(b, 0), BINS - 1);
            atomicAdd(&s_cnt[b], 1);
            atomicAdd(&s_sum[b], loss);
        }
    }
#undef LOADK

    __syncthreads();
    if (threadIdx.x < BINS) {
        pcnt[blockIdx.x * BINS + threadIdx.x] = s_cnt[threadIdx.x];
        psum[blockIdx.x * BINS + threadIdx.x] = s_sum[threadIdx.x];
        __threadfence();   // release: partials visible device-wide (to L3)
    }
    __syncthreads();

    __shared__ int s_last;
    if (threadIdx.x == 0)
        s_last = (atomicAdd(counter, 1) == nblk - 1);
    __syncthreads();
    if (!s_last) return;

    // ---- last block: reduce nblk x 10 partials and emit the scalar ----
    __threadfence();       // acquire: see all blocks' partials

    float cnt[BINS], sum[BINS];
    #pragma unroll
    for (int b = 0; b < BINS; ++b) { cnt[b] = 0.0f; sum[b] = 0.0f; }

    for (int blk = threadIdx.x; blk < nblk; blk += 256) {
        #pragma unroll
        for (int b = 0; b < BINS; ++b) {
            cnt[b] += (float)pcnt[blk * BINS + b];   // counts <= 65536: exact in f32
            sum[b] += psum[blk * BINS + b];
        }
    }

    __shared__ float sc[4][BINS], ss[4][BINS];
    #pragma unroll
    for (int b = 0; b < BINS; ++b) {
        const float c = dpp_reduce_add_lane63(cnt[b]);
        const float s = dpp_reduce_add_lane63(sum[b]);
        if (lane == 63) { sc[wv][b] = c; ss[wv][b] = s; }
    }
    __syncthreads();

    if (threadIdx.x == 0) {
        int n = 0;
        float acc = 0.0f;
        for (int b = 0; b < BINS; ++b) {
            const float c = sc[0][b] + sc[1][b] + sc[2][b] + sc[3][b];
            const float s = ss[0][b] + ss[1][b] + ss[2][b] + ss[3][b];
            if (c > 0.0f) { n += 1; acc += s / c; }
        }
        out[0] = acc / (float)max(n, 1);
    }
}

// ---------------- fallback path (tiny ws): R5's two-kernel scheme ----------
__global__ __launch_bounds__(256) void ghmc_pass1_atomic(
    const float* __restrict__ pred,
    const int*   __restrict__ target,
    int*   __restrict__ gcnt,
    float* __restrict__ gsum,
    int nrows)
{
    __shared__ int   s_cnt[BINS];
    __shared__ float s_sum[BINS];
    if (threadIdx.x < BINS) { s_cnt[threadIdx.x] = 0; s_sum[threadIdx.x] = 0.0f; }
    __syncthreads();

    const int lane = threadIdx.x & 63;
    const int wv   = threadIdx.x >> 6;
    const int base = blockIdx.x * 64 + wv * 16;
    const float NEG = -INFINITY;

    int tgt[16];
    #pragma unroll
    for (int k = 0; k < 16; ++k) tgt[k] = target[min(base + k, nrows - 1)];

    float4 C0[4], C1[4], C2[4], C3[4];
    float  pt[4];

#define LOADK(kk, pp) do {                                                    \
    const int r_ = min(base + (kk), nrows - 1);                               \
    const float4* rp_ = (const float4*)(pred + (size_t)r_ * NCLS);            \
    C0[pp] = rp_[lane]; C1[pp] = rp_[lane + 64]; C2[pp] = rp_[lane + 128];    \
    if (lane < 58) C3[pp] = rp_[lane + 192];                                  \
    else           C3[pp] = make_float4(NEG, NEG, NEG, NEG);                  \
    pt[pp] = pred[(size_t)r_ * NCLS + tgt[kk]];                               \
} while (0)

    LOADK(0, 0);  LOADK(1, 1);  LOADK(2, 2);

    #pragma unroll
    for (int k = 0; k < 16; ++k) {
        const int p = k & 3;
        if (k < 13) LOADK(k + 3, (k + 3) & 3);

        float s = exp16_sum(C0[p], C1[p], C2[p], C3[p]);
        s = dpp_reduce_add_lane63(s);

        if (lane == 63 && base + k < nrows) {
            const float loss = -pt[p] + __logf(s + EPSV);
            const float g = 1.0f - __expf(pt[p]) / s;
            int b = (int)floorf(g * 10.0f);
            b = min(max(b, 0), BINS - 1);
            atomicAdd(&s_cnt[b], 1);
            atomicAdd(&s_sum[b], loss);
        }
    }
#undef LOADK

    __syncthreads();
    if (threadIdx.x < BINS && s_cnt[threadIdx.x] > 0) {
        atomicAdd(&gcnt[threadIdx.x], s_cnt[threadIdx.x]);
        atomicAdd(&gsum[threadIdx.x], s_sum[threadIdx.x]);
    }
}

__global__ void ghmc_pass2_small(const int* __restrict__ gcnt,
                                 const float* __restrict__ gsum,
                                 float* __restrict__ out)
{
    if (threadIdx.x == 0 && blockIdx.x == 0) {
        int n = 0;
        float acc = 0.0f;
        for (int b = 0; b < BINS; ++b) {
            if (gcnt[b] > 0) { n += 1; acc += gsum[b] / (float)gcnt[b]; }
        }
        out[0] = acc / (float)max(n, 1);
    }
}

extern "C" void kernel_launch(void* const* d_in, const int* in_sizes, int n_in,
                              void* d_out, int out_size, void* d_ws, size_t ws_size,
                              hipStream_t stream)
{
    const float* pred   = (const float*)d_in[0];
    const int*   target = (const int*)d_in[1];
    const int nrows  = in_sizes[1];            // 65536
    const int blocks = (nrows + 63) / 64;      // 1024

    const size_t part_bytes = (((size_t)blocks * BINS * sizeof(int)) + 63) & ~(size_t)63;
    const size_t need = 64 + 2 * part_bytes;   // counter | pcnt | psum

    if (ws_size >= need) {
        int*   counter = (int*)d_ws;
        int*   pcnt = (int*)((char*)d_ws + 64);
        float* psum = (float*)((char*)d_ws + 64 + part_bytes);
        hipMemsetAsync(d_ws, 0, 64, stream);   // zero the arrival counter
        ghmc_fused<<<blocks, 256, 0, stream>>>(pred, target, counter, pcnt, psum,
                                               (float*)d_out, nrows, blocks);
    } else {
        int*   gcnt = (int*)d_ws;
        float* gsum = (float*)((char*)d_ws + 64);
        hipMemsetAsync(d_ws, 0, 128, stream);
        ghmc_pass1_atomic<<<blocks, 256, 0, stream>>>(pred, target, gcnt, gsum, nrows);
        ghmc_pass2_small<<<1, 64, 0, stream>>>(gcnt, gsum, (float*)d_out);
    }
}

// Round 8
// 80.600 us; speedup vs baseline: 1.0087x; 1.0053x over previous
//
#include <hip/hip_runtime.h>
#include <math.h>

#define BINS 10
#define NCLS 1000
#define EPSV 1e-8f

// Full-wave (64-lane) sum via DPP: 6 dependent VALU adds (~50 cy) instead of
// 6 ds_bpermute (~720 cy). Valid total lands in lane 63.
__device__ __forceinline__ float dpp_reduce_add_lane63(float x) {
    int t;
    t = __builtin_amdgcn_update_dpp(0, __float_as_int(x), 0x111, 0xF, 0xF, true); x += __int_as_float(t); // row_shr:1
    t = __builtin_amdgcn_update_dpp(0, __float_as_int(x), 0x112, 0xF, 0xF, true); x += __int_as_float(t); // row_shr:2
    t = __builtin_amdgcn_update_dpp(0, __float_as_int(x), 0x114, 0xF, 0xF, true); x += __int_as_float(t); // row_shr:4
    t = __builtin_amdgcn_update_dpp(0, __float_as_int(x), 0x118, 0xF, 0xF, true); x += __int_as_float(t); // row_shr:8
    t = __builtin_amdgcn_update_dpp(0, __float_as_int(x), 0x142, 0xF, 0xF, true); x += __int_as_float(t); // row_bcast:15
    t = __builtin_amdgcn_update_dpp(0, __float_as_int(x), 0x143, 0xF, 0xF, true); x += __int_as_float(t); // row_bcast:31
    return x; // lane 63 holds the full 64-lane sum
}

// Tree-shaped sum of exp over 16 values (depth 4).
__device__ __forceinline__ float exp16_sum(const float4& v0, const float4& v1,
                                           const float4& v2, const float4& v3) {
    float a0 = __expf(v0.x) + __expf(v0.y), a1 = __expf(v0.z) + __expf(v0.w);
    float a2 = __expf(v1.x) + __expf(v1.y), a3 = __expf(v1.z) + __expf(v1.w);
    float a4 = __expf(v2.x) + __expf(v2.y), a5 = __expf(v2.z) + __expf(v2.w);
    float a6 = __expf(v3.x) + __expf(v3.y), a7 = __expf(v3.z) + __expf(v3.w);
    float b0 = a0 + a1, b1 = a2 + a3, b2 = a4 + a5, b3 = a6 + a7;
    return (b0 + b1) + (b2 + b3);
}

// Fused kernel: R5's proven pass1 loop (1 row/stage, 4 register phases,
// 3 batches in flight/wave) + per-block partial stores + last-block-done
// reduction (release fence -> counter atomic -> acquire fence handles the
// cross-XCD L2 non-coherence; partials served from L3).
// R7 LESSON: __launch_bounds__(256,4) is a MIN waves/EU bound — LLVM then
// squeezed to 8 waves/EU (VGPR 64), serializing the pipeline (81us). Pin
// EXACT occupancy with amdgpu_waves_per_eu(4,4): VGPR budget 128, no squeeze.
__global__ __launch_bounds__(256)
__attribute__((amdgpu_waves_per_eu(4, 4)))
void ghmc_fused(
    const float* __restrict__ pred,
    const int*   __restrict__ target,
    int*   __restrict__ counter,
    int*   __restrict__ pcnt,
    float* __restrict__ psum,
    float* __restrict__ out,
    int nrows, int nblk)
{
    __shared__ int   s_cnt[BINS];
    __shared__ float s_sum[BINS];
    if (threadIdx.x < BINS) { s_cnt[threadIdx.x] = 0; s_sum[threadIdx.x] = 0.0f; }
    __syncthreads();

    const int lane = threadIdx.x & 63;
    const int wv   = threadIdx.x >> 6;
    const int base = blockIdx.x * 64 + wv * 16;   // wave owns rows base..base+15
    const float NEG = -INFINITY;

    // Preload all 16 targets (wave-uniform addresses -> scalar loads).
    int tgt[16];
    #pragma unroll
    for (int k = 0; k < 16; ++k) tgt[k] = target[min(base + k, nrows - 1)];

    float4 C0[4], C1[4], C2[4], C3[4];
    float  pt[4];

#define LOADK(kk, pp) do {                                                    \
    const int r_ = min(base + (kk), nrows - 1);                               \
    const float4* rp_ = (const float4*)(pred + (size_t)r_ * NCLS);            \
    C0[pp] = rp_[lane]; C1[pp] = rp_[lane + 64]; C2[pp] = rp_[lane + 128];    \
    if (lane < 58) C3[pp] = rp_[lane + 192];                                  \
    else           C3[pp] = make_float4(NEG, NEG, NEG, NEG);                  \
    pt[pp] = pred[(size_t)r_ * NCLS + tgt[kk]];                               \
} while (0)

    LOADK(0, 0);  LOADK(1, 1);  LOADK(2, 2);   // prologue: 3 batches in flight

    #pragma unroll
    for (int k = 0; k < 16; ++k) {
        const int p = k & 3;
        if (k < 13) LOADK(k + 3, (k + 3) & 3);   // keep 3 batches outstanding

        float s = exp16_sum(C0[p], C1[p], C2[p], C3[p]);
        s = dpp_reduce_add_lane63(s);

        if (lane == 63 && base + k < nrows) {
            const float loss = -pt[p] + __logf(s + EPSV);
            const float g = 1.0f - __expf(pt[p]) / s;
            int b = (int)floorf(g * 10.0f);
            b = min(max(b, 0), BINS - 1);
            atomicAdd(&s_cnt[b], 1);
            atomicAdd(&s_sum[b], loss);
        }
    }
#undef LOADK

    __syncthreads();
    if (threadIdx.x < BINS) {
        pcnt[blockIdx.x * BINS + threadIdx.x] = s_cnt[threadIdx.x];
        psum[blockIdx.x * BINS + threadIdx.x] = s_sum[threadIdx.x];
        __threadfence();   // release: partials visible device-wide (to L3)
    }
    __syncthreads();

    __shared__ int s_last;
    if (threadIdx.x == 0)
        s_last = (atomicAdd(counter, 1) == nblk - 1);
    __syncthreads();
    if (!s_last) return;

    // ---- last block: reduce nblk x 10 partials and emit the scalar ----
    __threadfence();       // acquire: see all blocks' partials

    float cnt[BINS], sum[BINS];
    #pragma unroll
    for (int b = 0; b < BINS; ++b) { cnt[b] = 0.0f; sum[b] = 0.0f; }

    for (int blk = threadIdx.x; blk < nblk; blk += 256) {
        #pragma unroll
        for (int b = 0; b < BINS; ++b) {
            cnt[b] += (float)pcnt[blk * BINS + b];   // counts <= 65536: exact in f32
            sum[b] += psum[blk * BINS + b];
        }
    }

    __shared__ float sc[4][BINS], ss[4][BINS];
    #pragma unroll
    for (int b = 0; b < BINS; ++b) {
        const float c = dpp_reduce_add_lane63(cnt[b]);
        const float s = dpp_reduce_add_lane63(sum[b]);
        if (lane == 63) { sc[wv][b] = c; ss[wv][b] = s; }
    }
    __syncthreads();

    if (threadIdx.x == 0) {
        int n = 0;
        float acc = 0.0f;
        for (int b = 0; b < BINS; ++b) {
            const float c = sc[0][b] + sc[1][b] + sc[2][b] + sc[3][b];
            const float s = ss[0][b] + ss[1][b] + ss[2][b] + ss[3][b];
            if (c > 0.0f) { n += 1; acc += s / c; }
        }
        out[0] = acc / (float)max(n, 1);
    }
}

// ---------------- fallback path (tiny ws): R5's two-kernel scheme ----------
__global__ __launch_bounds__(256) void ghmc_pass1_atomic(
    const float* __restrict__ pred,
    const int*   __restrict__ target,
    int*   __restrict__ gcnt,
    float* __restrict__ gsum,
    int nrows)
{
    __shared__ int   s_cnt[BINS];
    __shared__ float s_sum[BINS];
    if (threadIdx.x < BINS) { s_cnt[threadIdx.x] = 0; s_sum[threadIdx.x] = 0.0f; }
    __syncthreads();

    const int lane = threadIdx.x & 63;
    const int wv   = threadIdx.x >> 6;
    const int base = blockIdx.x * 64 + wv * 16;
    const float NEG = -INFINITY;

    int tgt[16];
    #pragma unroll
    for (int k = 0; k < 16; ++k) tgt[k] = target[min(base + k, nrows - 1)];

    float4 C0[4], C1[4], C2[4], C3[4];
    float  pt[4];

#define LOADK(kk, pp) do {                                                    \
    const int r_ = min(base + (kk), nrows - 1);                               \
    const float4* rp_ = (const float4*)(pred + (size_t)r_ * NCLS);            \
    C0[pp] = rp_[lane]; C1[pp] = rp_[lane + 64]; C2[pp] = rp_[lane + 128];    \
    if (lane < 58) C3[pp] = rp_[lane + 192];                                  \
    else           C3[pp] = make_float4(NEG, NEG, NEG, NEG);                  \
    pt[pp] = pred[(size_t)r_ * NCLS + tgt[kk]];                               \
} while (0)

    LOADK(0, 0);  LOADK(1, 1);  LOADK(2, 2);

    #pragma unroll
    for (int k = 0; k < 16; ++k) {
        const int p = k & 3;
        if (k < 13) LOADK(k + 3, (k + 3) & 3);

        float s = exp16_sum(C0[p], C1[p], C2[p], C3[p]);
        s = dpp_reduce_add_lane63(s);

        if (lane == 63 && base + k < nrows) {
            const float loss = -pt[p] + __logf(s + EPSV);
            const float g = 1.0f - __expf(pt[p]) / s;
            int b = (int)floorf(g * 10.0f);
            b = min(max(b, 0), BINS - 1);
            atomicAdd(&s_cnt[b], 1);
            atomicAdd(&s_sum[b], loss);
        }
    }
#undef LOADK

    __syncthreads();
    if (threadIdx.x < BINS && s_cnt[threadIdx.x] > 0) {
        atomicAdd(&gcnt[threadIdx.x], s_cnt[threadIdx.x]);
        atomicAdd(&gsum[threadIdx.x], s_sum[threadIdx.x]);
    }
}

__global__ void ghmc_pass2_small(const int* __restrict__ gcnt,
                                 const float* __restrict__ gsum,
                                 float* __restrict__ out)
{
    if (threadIdx.x == 0 && blockIdx.x == 0) {
        int n = 0;
        float acc = 0.0f;
        for (int b = 0; b < BINS; ++b) {
            if (gcnt[b] > 0) { n += 1; acc += gsum[b] / (float)gcnt[b]; }
        }
        out[0] = acc / (float)max(n, 1);
    }
}

extern "C" void kernel_launch(void* const* d_in, const int* in_sizes, int n_in,
                              void* d_out, int out_size, void* d_ws, size_t ws_size,
                              hipStream_t stream)
{
    const float* pred   = (const float*)d_in[0];
    const int*   target = (const int*)d_in[1];
    const int nrows  = in_sizes[1];            // 65536
    const int blocks = (nrows + 63) / 64;      // 1024

    const size_t part_bytes = (((size_t)blocks * BINS * sizeof(int)) + 63) & ~(size_t)63;
    const size_t need = 64 + 2 * part_bytes;   // counter | pcnt | psum

    if (ws_size >= need) {
        int*   counter = (int*)d_ws;
        int*   pcnt = (int*)((char*)d_ws + 64);
        float* psum = (float*)((char*)d_ws + 64 + part_bytes);
        hipMemsetAsync(d_ws, 0, 64, stream);   // zero the arrival counter
        ghmc_fused<<<blocks, 256, 0, stream>>>(pred, target, counter, pcnt, psum,
                                               (float*)d_out, nrows, blocks);
    } else {
        int*   gcnt = (int*)d_ws;
        float* gsum = (float*)((char*)d_ws + 64);
        hipMemsetAsync(d_ws, 0, 128, stream);
        ghmc_pass1_atomic<<<blocks, 256, 0, stream>>>(pred, target, gcnt, gsum, nrows);
        ghmc_pass2_small<<<1, 64, 0, stream>>>(gcnt, gsum, (float*)d_out);
    }
}

// Round 9
// 55.528 us; speedup vs baseline: 1.4641x; 1.4515x over previous
//
#include <hip/hip_runtime.h>
#include <math.h>

#define BINS 10
#define NCLS 1000
#define EPSV 1e-8f
#define RPW  8                      // rows per wave
#define RPB  (4 * RPW)              // rows per block (4 waves)

// Full-wave (64-lane) sum via DPP: 6 dependent VALU adds (~50 cy) instead of
// 6 ds_bpermute (~720 cy). Valid total lands in lane 63.
__device__ __forceinline__ float dpp_reduce_add_lane63(float x) {
    int t;
    t = __builtin_amdgcn_update_dpp(0, __float_as_int(x), 0x111, 0xF, 0xF, true); x += __int_as_float(t); // row_shr:1
    t = __builtin_amdgcn_update_dpp(0, __float_as_int(x), 0x112, 0xF, 0xF, true); x += __int_as_float(t); // row_shr:2
    t = __builtin_amdgcn_update_dpp(0, __float_as_int(x), 0x114, 0xF, 0xF, true); x += __int_as_float(t); // row_shr:4
    t = __builtin_amdgcn_update_dpp(0, __float_as_int(x), 0x118, 0xF, 0xF, true); x += __int_as_float(t); // row_shr:8
    t = __builtin_amdgcn_update_dpp(0, __float_as_int(x), 0x142, 0xF, 0xF, true); x += __int_as_float(t); // row_bcast:15
    t = __builtin_amdgcn_update_dpp(0, __float_as_int(x), 0x143, 0xF, 0xF, true); x += __int_as_float(t); // row_bcast:31
    return x; // lane 63 holds the full 64-lane sum
}

// Tree-shaped sum of exp over 16 values (depth 4).
__device__ __forceinline__ float exp16_sum(const float4& v0, const float4& v1,
                                           const float4& v2, const float4& v3) {
    float a0 = __expf(v0.x) + __expf(v0.y), a1 = __expf(v0.z) + __expf(v0.w);
    float a2 = __expf(v1.x) + __expf(v1.y), a3 = __expf(v1.z) + __expf(v1.w);
    float a4 = __expf(v2.x) + __expf(v2.y), a5 = __expf(v2.z) + __expf(v2.w);
    float a6 = __expf(v3.x) + __expf(v3.y), a7 = __expf(v3.z) + __expf(v3.w);
    float b0 = a0 + a1, b1 = a2 + a3, b2 = a4 + a5, b3 = a6 + a7;
    return (b0 + b1) + (b2 + b3);
}

// R5's proven main loop (1 row/stage, 4 register phases, 3 batches in
// flight/wave), now at 2048 blocks x 32 rows (8 blocks/CU) to probe whether
// pass1 was occupancy-starved. NO fused tail, NO extra launch-bounds attrs —
// R7/R8 showed the fused tail collapses the allocation to 64 VGPR and
// serializes the pipeline (81us). Partials stored SoA: pcnt[b*nblk + blk].
__global__ __launch_bounds__(256) void ghmc_pass1(
    const float* __restrict__ pred,
    const int*   __restrict__ target,
    int*   __restrict__ pcnt,
    float* __restrict__ psum,
    int nrows, int nblk)
{
    __shared__ int   s_cnt[BINS];
    __shared__ float s_sum[BINS];
    if (threadIdx.x < BINS) { s_cnt[threadIdx.x] = 0; s_sum[threadIdx.x] = 0.0f; }
    __syncthreads();

    const int lane = threadIdx.x & 63;
    const int wv   = threadIdx.x >> 6;
    const int base = blockIdx.x * RPB + wv * RPW;   // wave owns RPW consecutive rows
    const float NEG = -INFINITY;

    // Preload targets (wave-uniform addresses -> scalar loads).
    int tgt[RPW];
    #pragma unroll
    for (int k = 0; k < RPW; ++k) tgt[k] = target[min(base + k, nrows - 1)];

    float4 C0[4], C1[4], C2[4], C3[4];
    float  pt[4];

#define LOADK(kk, pp) do {                                                    \
    const int r_ = min(base + (kk), nrows - 1);                               \
    const float4* rp_ = (const float4*)(pred + (size_t)r_ * NCLS);            \
    C0[pp] = rp_[lane]; C1[pp] = rp_[lane + 64]; C2[pp] = rp_[lane + 128];    \
    if (lane < 58) C3[pp] = rp_[lane + 192];                                  \
    else           C3[pp] = make_float4(NEG, NEG, NEG, NEG);                  \
    pt[pp] = pred[(size_t)r_ * NCLS + tgt[kk]];                               \
} while (0)

    LOADK(0, 0);  LOADK(1, 1);  LOADK(2, 2);   // prologue: 3 batches in flight

    #pragma unroll
    for (int k = 0; k < RPW; ++k) {
        const int p = k & 3;
        if (k < RPW - 3) LOADK(k + 3, (k + 3) & 3);   // keep 3 outstanding

        float s = exp16_sum(C0[p], C1[p], C2[p], C3[p]);
        s = dpp_reduce_add_lane63(s);

        if (lane == 63 && base + k < nrows) {
            const float loss = -pt[p] + __logf(s + EPSV);
            const float g = 1.0f - __expf(pt[p]) / s;
            int b = (int)floorf(g * 10.0f);
            b = min(max(b, 0), BINS - 1);
            atomicAdd(&s_cnt[b], 1);
            atomicAdd(&s_sum[b], loss);
        }
    }
#undef LOADK

    __syncthreads();
    if (threadIdx.x < BINS) {   // SoA slot: full overwrite, deterministic
        pcnt[threadIdx.x * nblk + blockIdx.x] = s_cnt[threadIdx.x];
        psum[threadIdx.x * nblk + blockIdx.x] = s_sum[threadIdx.x];
    }
}

// Pass 2: reduce BINS x nblk SoA partials (coalesced int4/float4 strided
// loads), then combine the 10 bins.
// out = sum_b (loss_sum[b] / counts[b]) / n_nonempty
__global__ __launch_bounds__(256) void ghmc_pass2(
    const int* __restrict__ pcnt,
    const float* __restrict__ psum,
    float* __restrict__ out, int nblk)
{
    const int lane = threadIdx.x & 63;
    const int wv   = threadIdx.x >> 6;

    float cnt[BINS], sum[BINS];
    #pragma unroll
    for (int b = 0; b < BINS; ++b) { cnt[b] = 0.0f; sum[b] = 0.0f; }

    if ((nblk & 3) == 0) {
        for (int i = threadIdx.x * 4; i < nblk; i += 1024) {
            #pragma unroll
            for (int b = 0; b < BINS; ++b) {
                const int4   c4 = *(const int4*)  (pcnt + (size_t)b * nblk + i);
                const float4 s4 = *(const float4*)(psum + (size_t)b * nblk + i);
                cnt[b] += (float)(c4.x + c4.y + c4.z + c4.w); // counts <= 65536: exact in f32
                sum[b] += (s4.x + s4.y) + (s4.z + s4.w);
            }
        }
    } else {
        for (int i = threadIdx.x; i < nblk; i += 256) {
            #pragma unroll
            for (int b = 0; b < BINS; ++b) {
                cnt[b] += (float)pcnt[(size_t)b * nblk + i];
                sum[b] += psum[(size_t)b * nblk + i];
            }
        }
    }

    __shared__ float sc[4][BINS], ss[4][BINS];
    #pragma unroll
    for (int b = 0; b < BINS; ++b) {
        const float c = dpp_reduce_add_lane63(cnt[b]);
        const float s = dpp_reduce_add_lane63(sum[b]);
        if (lane == 63) { sc[wv][b] = c; ss[wv][b] = s; }
    }
    __syncthreads();

    if (threadIdx.x == 0) {
        int n = 0;
        float acc = 0.0f;
        for (int b = 0; b < BINS; ++b) {
            const float c = sc[0][b] + sc[1][b] + sc[2][b] + sc[3][b];
            const float s = ss[0][b] + ss[1][b] + ss[2][b] + ss[3][b];
            if (c > 0.0f) { n += 1; acc += s / c; }
        }
        out[0] = acc / (float)max(n, 1);
    }
}

// ---------------- fallback path (tiny ws): atomics + memset ----------------
__global__ __launch_bounds__(256) void ghmc_pass1_atomic(
    const float* __restrict__ pred,
    const int*   __restrict__ target,
    int*   __restrict__ gcnt,
    float* __restrict__ gsum,
    int nrows)
{
    __shared__ int   s_cnt[BINS];
    __shared__ float s_sum[BINS];
    if (threadIdx.x < BINS) { s_cnt[threadIdx.x] = 0; s_sum[threadIdx.x] = 0.0f; }
    __syncthreads();

    const int lane = threadIdx.x & 63;
    const int wv   = threadIdx.x >> 6;
    const int base = blockIdx.x * RPB + wv * RPW;
    const float NEG = -INFINITY;

    int tgt[RPW];
    #pragma unroll
    for (int k = 0; k < RPW; ++k) tgt[k] = target[min(base + k, nrows - 1)];

    float4 C0[4], C1[4], C2[4], C3[4];
    float  pt[4];

#define LOADK(kk, pp) do {                                                    \
    const int r_ = min(base + (kk), nrows - 1);                               \
    const float4* rp_ = (const float4*)(pred + (size_t)r_ * NCLS);            \
    C0[pp] = rp_[lane]; C1[pp] = rp_[lane + 64]; C2[pp] = rp_[lane + 128];    \
    if (lane < 58) C3[pp] = rp_[lane + 192];                                  \
    else           C3[pp] = make_float4(NEG, NEG, NEG, NEG);                  \
    pt[pp] = pred[(size_t)r_ * NCLS + tgt[kk]];                               \
} while (0)

    LOADK(0, 0);  LOADK(1, 1);  LOADK(2, 2);

    #pragma unroll
    for (int k = 0; k < RPW; ++k) {
        const int p = k & 3;
        if (k < RPW - 3) LOADK(k + 3, (k + 3) & 3);

        float s = exp16_sum(C0[p], C1[p], C2[p], C3[p]);
        s = dpp_reduce_add_lane63(s);

        if (lane == 63 && base + k < nrows) {
            const float loss = -pt[p] + __logf(s + EPSV);
            const float g = 1.0f - __expf(pt[p]) / s;
            int b = (int)floorf(g * 10.0f);
            b = min(max(b, 0), BINS - 1);
            atomicAdd(&s_cnt[b], 1);
            atomicAdd(&s_sum[b], loss);
        }
    }
#undef LOADK

    __syncthreads();
    if (threadIdx.x < BINS && s_cnt[threadIdx.x] > 0) {
        atomicAdd(&gcnt[threadIdx.x], s_cnt[threadIdx.x]);
        atomicAdd(&gsum[threadIdx.x], s_sum[threadIdx.x]);
    }
}

__global__ void ghmc_pass2_small(const int* __restrict__ gcnt,
                                 const float* __restrict__ gsum,
                                 float* __restrict__ out)
{
    if (threadIdx.x == 0 && blockIdx.x == 0) {
        int n = 0;
        float acc = 0.0f;
        for (int b = 0; b < BINS; ++b) {
            if (gcnt[b] > 0) { n += 1; acc += gsum[b] / (float)gcnt[b]; }
        }
        out[0] = acc / (float)max(n, 1);
    }
}

extern "C" void kernel_launch(void* const* d_in, const int* in_sizes, int n_in,
                              void* d_out, int out_size, void* d_ws, size_t ws_size,
                              hipStream_t stream)
{
    const float* pred   = (const float*)d_in[0];
    const int*   target = (const int*)d_in[1];
    const int nrows  = in_sizes[1];                  // 65536
    const int blocks = (nrows + RPB - 1) / RPB;      // 2048

    const size_t part_bytes = (((size_t)blocks * BINS * sizeof(int)) + 63) & ~(size_t)63;
    const size_t need = 2 * part_bytes;              // pcnt | psum (SoA)

    if (ws_size >= need) {
        int*   pcnt = (int*)d_ws;
        float* psum = (float*)((char*)d_ws + part_bytes);
        ghmc_pass1<<<blocks, 256, 0, stream>>>(pred, target, pcnt, psum,
                                               nrows, blocks);
        ghmc_pass2<<<1, 256, 0, stream>>>(pcnt, psum, (float*)d_out, blocks);
    } else {
        int*   gcnt = (int*)d_ws;
        float* gsum = (float*)((char*)d_ws + 64);
        hipMemsetAsync(d_ws, 0, 128, stream);
        ghmc_pass1_atomic<<<blocks, 256, 0, stream>>>(pred, target, gcnt, gsum, nrows);
        ghmc_pass2_small<<<1, 64, 0, stream>>>(gcnt, gsum, (float*)d_out);
    }
}

// Round 10
// 51.437 us; speedup vs baseline: 1.5806x; 1.0795x over previous
//
#include <hip/hip_runtime.h>
#include <math.h>

#define BINS 10
#define NCLS 1000
#define EPSV 1e-8f
#define RPW  16                     // rows per wave (R5 proven: 3/16 drain fraction)
#define RPB  (4 * RPW)              // rows per block (4 waves) = 64

// Full-wave (64-lane) sum via DPP: 6 dependent VALU adds (~50 cy) instead of
// 6 ds_bpermute (~720 cy). Valid total lands in lane 63.
__device__ __forceinline__ float dpp_reduce_add_lane63(float x) {
    int t;
    t = __builtin_amdgcn_update_dpp(0, __float_as_int(x), 0x111, 0xF, 0xF, true); x += __int_as_float(t); // row_shr:1
    t = __builtin_amdgcn_update_dpp(0, __float_as_int(x), 0x112, 0xF, 0xF, true); x += __int_as_float(t); // row_shr:2
    t = __builtin_amdgcn_update_dpp(0, __float_as_int(x), 0x114, 0xF, 0xF, true); x += __int_as_float(t); // row_shr:4
    t = __builtin_amdgcn_update_dpp(0, __float_as_int(x), 0x118, 0xF, 0xF, true); x += __int_as_float(t); // row_shr:8
    t = __builtin_amdgcn_update_dpp(0, __float_as_int(x), 0x142, 0xF, 0xF, true); x += __int_as_float(t); // row_bcast:15
    t = __builtin_amdgcn_update_dpp(0, __float_as_int(x), 0x143, 0xF, 0xF, true); x += __int_as_float(t); // row_bcast:31
    return x; // lane 63 holds the full 64-lane sum
}

// Tree-shaped sum of exp over 16 values (depth 4).
__device__ __forceinline__ float exp16_sum(const float4& v0, const float4& v1,
                                           const float4& v2, const float4& v3) {
    float a0 = __expf(v0.x) + __expf(v0.y), a1 = __expf(v0.z) + __expf(v0.w);
    float a2 = __expf(v1.x) + __expf(v1.y), a3 = __expf(v1.z) + __expf(v1.w);
    float a4 = __expf(v2.x) + __expf(v2.y), a5 = __expf(v2.z) + __expf(v2.w);
    float a6 = __expf(v3.x) + __expf(v3.y), a7 = __expf(v3.z) + __expf(v3.w);
    float b0 = a0 + a1, b1 = a2 + a3, b2 = a4 + a5, b3 = a6 + a7;
    return (b0 + b1) + (b2 + b3);
}

// R5's proven main loop: 1 row/stage, 4 register phases, 3 batches in
// flight/wave, 1024 blocks x 64 rows (R9 showed 2048x32 regresses: drain
// fraction 3/8 vs 3/16). EXACT=true (nrows % RPB == 0, the actual case)
// drops all min() clamps and bounds checks: target preloads become pure
// wave-uniform s_loads, LOADK loses the clamp ALU, emit loses its compare.
// No fused tail (R7/R8: tail presence collapses regalloc to 64 VGPR, 81us).
// Partials stored SoA: pcnt[b*nblk + blk] for coalesced pass2 reads.
template<bool EXACT>
__global__ __launch_bounds__(256) void ghmc_pass1(
    const float* __restrict__ pred,
    const int*   __restrict__ target,
    int*   __restrict__ pcnt,
    float* __restrict__ psum,
    int nrows, int nblk)
{
    __shared__ int   s_cnt[BINS];
    __shared__ float s_sum[BINS];
    if (threadIdx.x < BINS) { s_cnt[threadIdx.x] = 0; s_sum[threadIdx.x] = 0.0f; }
    __syncthreads();

    const int lane = threadIdx.x & 63;
    const int wv   = threadIdx.x >> 6;
    const int base = blockIdx.x * RPB + wv * RPW;   // wave owns RPW consecutive rows
    const float NEG = -INFINITY;

    // Preload targets (wave-uniform addresses -> scalar loads).
    int tgt[RPW];
    #pragma unroll
    for (int k = 0; k < RPW; ++k)
        tgt[k] = target[EXACT ? (base + k) : min(base + k, nrows - 1)];

    float4 C0[4], C1[4], C2[4], C3[4];
    float  pt[4];

#define LOADK(kk, pp) do {                                                    \
    const int r_ = EXACT ? (base + (kk)) : min(base + (kk), nrows - 1);       \
    const float4* rp_ = (const float4*)(pred + (size_t)r_ * NCLS);            \
    C0[pp] = rp_[lane]; C1[pp] = rp_[lane + 64]; C2[pp] = rp_[lane + 128];    \
    if (lane < 58) C3[pp] = rp_[lane + 192];                                  \
    else           C3[pp] = make_float4(NEG, NEG, NEG, NEG);                  \
    pt[pp] = pred[(size_t)r_ * NCLS + tgt[kk]];                               \
} while (0)

    LOADK(0, 0);  LOADK(1, 1);  LOADK(2, 2);   // prologue: 3 batches in flight

    #pragma unroll
    for (int k = 0; k < RPW; ++k) {
        const int p = k & 3;
        if (k < RPW - 3) LOADK(k + 3, (k + 3) & 3);   // keep 3 outstanding

        float s = exp16_sum(C0[p], C1[p], C2[p], C3[p]);
        s = dpp_reduce_add_lane63(s);

        if (lane == 63 && (EXACT || base + k < nrows)) {
            const float loss = -pt[p] + __logf(s + EPSV);
            const float g = 1.0f - __expf(pt[p]) / s;
            int b = (int)floorf(g * 10.0f);
            b = min(max(b, 0), BINS - 1);
            atomicAdd(&s_cnt[b], 1);
            atomicAdd(&s_sum[b], loss);
        }
    }
#undef LOADK

    __syncthreads();
    if (threadIdx.x < BINS) {   // SoA slot: full overwrite, deterministic
        pcnt[threadIdx.x * nblk + blockIdx.x] = s_cnt[threadIdx.x];
        psum[threadIdx.x * nblk + blockIdx.x] = s_sum[threadIdx.x];
    }
}

// Pass 2: reduce BINS x nblk SoA partials (coalesced int4/float4 loads),
// then combine: out = sum_b (loss_sum[b] / counts[b]) / n_nonempty
__global__ __launch_bounds__(256) void ghmc_pass2(
    const int* __restrict__ pcnt,
    const float* __restrict__ psum,
    float* __restrict__ out, int nblk)
{
    const int lane = threadIdx.x & 63;
    const int wv   = threadIdx.x >> 6;

    float cnt[BINS], sum[BINS];
    #pragma unroll
    for (int b = 0; b < BINS; ++b) { cnt[b] = 0.0f; sum[b] = 0.0f; }

    if ((nblk & 3) == 0) {
        for (int i = threadIdx.x * 4; i < nblk; i += 1024) {
            #pragma unroll
            for (int b = 0; b < BINS; ++b) {
                const int4   c4 = *(const int4*)  (pcnt + (size_t)b * nblk + i);
                const float4 s4 = *(const float4*)(psum + (size_t)b * nblk + i);
                cnt[b] += (float)(c4.x + c4.y + c4.z + c4.w); // counts <= 65536: exact in f32
                sum[b] += (s4.x + s4.y) + (s4.z + s4.w);
            }
        }
    } else {
        for (int i = threadIdx.x; i < nblk; i += 256) {
            #pragma unroll
            for (int b = 0; b < BINS; ++b) {
                cnt[b] += (float)pcnt[(size_t)b * nblk + i];
                sum[b] += psum[(size_t)b * nblk + i];
            }
        }
    }

    __shared__ float sc[4][BINS], ss[4][BINS];
    #pragma unroll
    for (int b = 0; b < BINS; ++b) {
        const float c = dpp_reduce_add_lane63(cnt[b]);
        const float s = dpp_reduce_add_lane63(sum[b]);
        if (lane == 63) { sc[wv][b] = c; ss[wv][b] = s; }
    }
    __syncthreads();

    if (threadIdx.x == 0) {
        int n = 0;
        float acc = 0.0f;
        for (int b = 0; b < BINS; ++b) {
            const float c = sc[0][b] + sc[1][b] + sc[2][b] + sc[3][b];
            const float s = ss[0][b] + ss[1][b] + ss[2][b] + ss[3][b];
            if (c > 0.0f) { n += 1; acc += s / c; }
        }
        out[0] = acc / (float)max(n, 1);
    }
}

// ---------------- fallback path (tiny ws): atomics + memset ----------------
__global__ __launch_bounds__(256) void ghmc_pass1_atomic(
    const float* __restrict__ pred,
    const int*   __restrict__ target,
    int*   __restrict__ gcnt,
    float* __restrict__ gsum,
    int nrows)
{
    __shared__ int   s_cnt[BINS];
    __shared__ float s_sum[BINS];
    if (threadIdx.x < BINS) { s_cnt[threadIdx.x] = 0; s_sum[threadIdx.x] = 0.0f; }
    __syncthreads();

    const int lane = threadIdx.x & 63;
    const int wv   = threadIdx.x >> 6;
    const int base = blockIdx.x * RPB + wv * RPW;
    const float NEG = -INFINITY;

    int tgt[RPW];
    #pragma unroll
    for (int k = 0; k < RPW; ++k) tgt[k] = target[min(base + k, nrows - 1)];

    float4 C0[4], C1[4], C2[4], C3[4];
    float  pt[4];

#define LOADK(kk, pp) do {                                                    \
    const int r_ = min(base + (kk), nrows - 1);                               \
    const float4* rp_ = (const float4*)(pred + (size_t)r_ * NCLS);            \
    C0[pp] = rp_[lane]; C1[pp] = rp_[lane + 64]; C2[pp] = rp_[lane + 128];    \
    if (lane < 58) C3[pp] = rp_[lane + 192];                                  \
    else           C3[pp] = make_float4(NEG, NEG, NEG, NEG);                  \
    pt[pp] = pred[(size_t)r_ * NCLS + tgt[kk]];                               \
} while (0)

    LOADK(0, 0);  LOADK(1, 1);  LOADK(2, 2);

    #pragma unroll
    for (int k = 0; k < RPW; ++k) {
        const int p = k & 3;
        if (k < RPW - 3) LOADK(k + 3, (k + 3) & 3);

        float s = exp16_sum(C0[p], C1[p], C2[p], C3[p]);
        s = dpp_reduce_add_lane63(s);

        if (lane == 63 && base + k < nrows) {
            const float loss = -pt[p] + __logf(s + EPSV);
            const float g = 1.0f - __expf(pt[p]) / s;
            int b = (int)floorf(g * 10.0f);
            b = min(max(b, 0), BINS - 1);
            atomicAdd(&s_cnt[b], 1);
            atomicAdd(&s_sum[b], loss);
        }
    }
#undef LOADK

    __syncthreads();
    if (threadIdx.x < BINS && s_cnt[threadIdx.x] > 0) {
        atomicAdd(&gcnt[threadIdx.x], s_cnt[threadIdx.x]);
        atomicAdd(&gsum[threadIdx.x], s_sum[threadIdx.x]);
    }
}

__global__ void ghmc_pass2_small(const int* __restrict__ gcnt,
                                 const float* __restrict__ gsum,
                                 float* __restrict__ out)
{
    if (threadIdx.x == 0 && blockIdx.x == 0) {
        int n = 0;
        float acc = 0.0f;
        for (int b = 0; b < BINS; ++b) {
            if (gcnt[b] > 0) { n += 1; acc += gsum[b] / (float)gcnt[b]; }
        }
        out[0] = acc / (float)max(n, 1);
    }
}

extern "C" void kernel_launch(void* const* d_in, const int* in_sizes, int n_in,
                              void* d_out, int out_size, void* d_ws, size_t ws_size,
                              hipStream_t stream)
{
    const float* pred   = (const float*)d_in[0];
    const int*   target = (const int*)d_in[1];
    const int nrows  = in_sizes[1];                  // 65536
    const int blocks = (nrows + RPB - 1) / RPB;      // 1024

    const size_t part_bytes = (((size_t)blocks * BINS * sizeof(int)) + 63) & ~(size_t)63;
    const size_t need = 2 * part_bytes;              // pcnt | psum (SoA)

    if (ws_size >= need) {
        int*   pcnt = (int*)d_ws;
        float* psum = (float*)((char*)d_ws + part_bytes);
        if (nrows % RPB == 0)
            ghmc_pass1<true><<<blocks, 256, 0, stream>>>(pred, target, pcnt, psum,
                                                         nrows, blocks);
        else
            ghmc_pass1<false><<<blocks, 256, 0, stream>>>(pred, target, pcnt, psum,
                                                          nrows, blocks);
        ghmc_pass2<<<1, 256, 0, stream>>>(pcnt, psum, (float*)d_out, blocks);
    } else {
        int*   gcnt = (int*)d_ws;
        float* gsum = (float*)((char*)d_ws + 64);
        hipMemsetAsync(d_ws, 0, 128, stream);
        ghmc_pass1_atomic<<<blocks, 256, 0, stream>>>(pred, target, gcnt, gsum, nrows);
        ghmc_pass2_small<<<1, 64, 0, stream>>>(gcnt, gsum, (float*)d_out);
    }
}